// Round 17
// baseline (46.124 us; speedup 1.0000x reference)
//
#include <hip/hip_runtime.h>
#include <math.h>

// ---------------------------------------------------------------------------
// ZBL repulsion, R17: R16 + off-critical-path chains (T15 deferred pipeline).
//  - DEFERRED SCAN: scan+deposit of iteration t-1's (runkey,runsum) executes
//    alongside iteration t's compute (independent chains -> interleaved)
//  - z8 PREFETCH: ds_read_u8 for stage t+1's 8 indices issued at t
//  - za INLINE: exp2(ae*log2(z)) in VALU (kills the 2nd LDS chain hop)
//  - rest = R16: 4 pairs/thread vector loads, depth-3 stream pipeline,
//    1024-thr persistent blocks, LDS z8 (100 KB) + CAP slots, flush+epilogue
// ---------------------------------------------------------------------------

#define LOG2E 1.4426950408889634f
#define BLK   1024
#define NBLK  256
#define PPT   4
#define STRD  (BLK * PPT)
#define CAP   2048

static __device__ __forceinline__ float rcpf_(float x)  { return __builtin_amdgcn_rcpf(x); }
static __device__ __forceinline__ float rsqf_(float x)  { return __builtin_amdgcn_rsqf(x); }
static __device__ __forceinline__ float exp2f_(float x) { return __builtin_amdgcn_exp2f(x); }
static __device__ __forceinline__ float log2f_(float x) { return __builtin_amdgcn_logf(x); }

struct G4 { int ii0,ii1,ii2,ii3, jj0,jj1,jj2,jj3;
            float bm0,bm1,bm2,bm3;
            float dx0,dx1,dx2,dx3, dy0,dy1,dy2,dy3, dz0,dz1,dz2,dz3; };

__global__ void zbl_k0(const float* __restrict__ an,
                       unsigned char* __restrict__ z8,
                       float* __restrict__ out, int n) {
    int i = blockIdx.x * blockDim.x + threadIdx.x;
    if (i >= n) return;
    int z = (int)(an[i] + 0.5f);
    z8[i] = (unsigned char)min(max(z, 1), 255);
    out[i] = 0.0f;
}

static __device__ __forceinline__ G4 loadG4(const int* __restrict__ idx_i,
                                            const int* __restrict__ idx_j,
                                            const float* __restrict__ bmk,
                                            const float* __restrict__ disp,
                                            int p0, int cend) {
    G4 g;
    if (p0 + PPT <= cend) {
        const int4   ii = *reinterpret_cast<const int4*>(idx_i + p0);
        const int4   jj = *reinterpret_cast<const int4*>(idx_j + p0);
        const float4 bm = *reinterpret_cast<const float4*>(bmk + p0);
        const float4* d4 = reinterpret_cast<const float4*>(disp + (long)p0 * 3);
        const float4 d0 = d4[0], d1 = d4[1], d2 = d4[2];
        g.ii0=ii.x; g.ii1=ii.y; g.ii2=ii.z; g.ii3=ii.w;
        g.jj0=jj.x; g.jj1=jj.y; g.jj2=jj.z; g.jj3=jj.w;
        g.bm0=bm.x; g.bm1=bm.y; g.bm2=bm.z; g.bm3=bm.w;
        g.dx0=d0.x; g.dy0=d0.y; g.dz0=d0.z;
        g.dx1=d0.w; g.dy1=d1.x; g.dz1=d1.y;
        g.dx2=d1.z; g.dy2=d1.w; g.dz2=d2.x;
        g.dx3=d2.y; g.dy3=d2.z; g.dz3=d2.w;
    } else {
        int   ii[4], jj[4]; float bm[4], dx[4], dy[4], dz[4];
        #pragma unroll
        for (int k = 0; k < PPT; ++k) {
            const int p = p0 + k;
            if (p < cend) {
                ii[k] = idx_i[p]; jj[k] = idx_j[p]; bm[k] = bmk[p];
                const float* dp = disp + (long)p * 3;
                dx[k] = dp[0]; dy[k] = dp[1]; dz[k] = dp[2];
            } else { ii[k] = -1; jj[k] = 0; bm[k] = 0.f; dx[k]=dy[k]=dz[k]=0.f; }
        }
        g.ii0=ii[0]; g.ii1=ii[1]; g.ii2=ii[2]; g.ii3=ii[3];
        g.jj0=jj[0]; g.jj1=jj[1]; g.jj2=jj[2]; g.jj3=jj[3];
        g.bm0=bm[0]; g.bm1=bm[1]; g.bm2=bm[2]; g.bm3=bm[3];
        g.dx0=dx[0]; g.dx1=dx[1]; g.dx2=dx[2]; g.dx3=dx[3];
        g.dy0=dy[0]; g.dy1=dy[1]; g.dy2=dy[2]; g.dy3=dy[3];
        g.dz0=dz[0]; g.dz1=dz[1]; g.dz2=dz[2]; g.dz3=dz[3];
    }
    return g;
}

__global__ __launch_bounds__(BLK) void zbl_pair_kernel(
    const float* __restrict__ disp,
    const int*   __restrict__ idx_i,       // sorted
    const int*   __restrict__ idx_j,
    const float* __restrict__ batch_mask,
    const unsigned char* __restrict__ z8g,
    const float* __restrict__ a_coef_ptr,
    const float* __restrict__ a_exp_ptr,
    const float* __restrict__ phi_c,
    const float* __restrict__ phi_e,
    float* __restrict__ out_acc,           // [N] zeroed accumulator
    int nA, int nP)
{
    extern __shared__ unsigned char smem[];
    const int nA_pad = (nA + 15) & ~15;
    unsigned char* s_z8  = smem;
    float*         s_acc = (float*)(smem + nA_pad);

    const int tid = threadIdx.x;

    {
        const int nw = nA >> 4;
        const uint4* g4 = reinterpret_cast<const uint4*>(z8g);
        uint4* s4 = reinterpret_cast<uint4*>(s_z8);
        for (int i = tid; i < nw; i += BLK) s4[i] = g4[i];
        for (int i = (nw << 4) + tid; i < nA; i += BLK) s_z8[i] = z8g[i];
    }
    for (int i = tid; i < CAP; i += BLK) s_acc[i] = 0.0f;

    const float ae     = fabsf(a_exp_ptr[0]);
    const float ac_inv = rcpf_(fmaxf(fabsf(a_coef_ptr[0]), 1e-10f));
    float c0 = fabsf(phi_c[0]), c1 = fabsf(phi_c[1]);
    float c2 = fabsf(phi_c[2]), c3 = fabsf(phi_c[3]);
    const float cinv = rcpf_(fmaxf(c0 + c1 + c2 + c3, 1e-10f));
    c0 *= cinv; c1 *= cinv; c2 *= cinv; c3 *= cinv;
    const float e0 = fmaxf(fabsf(phi_e[0]), 1e-10f);
    const float e1 = fmaxf(fabsf(phi_e[1]), 1e-10f);
    const float e2 = fmaxf(fabsf(phi_e[2]), 1e-10f);
    const float e3 = fmaxf(fabsf(phi_e[3]), 1e-10f);

    int chunk = (nP + NBLK - 1) / NBLK;
    chunk = (chunk + PPT - 1) & ~(PPT - 1);
    const int cbeg = min(blockIdx.x * chunk, nP);
    const int cend = min(cbeg + chunk, nP);
    const int lane = tid & 63;
    const int kbase = (cbeg < nP) ? idx_i[cbeg] : 0;

    __syncthreads();   // z8 table + slots ready

#define PAIR_REP(II, JJ, ZI, ZJ, BM, DX, DY, DZ, rep)                           \
    {                                                                           \
        rep = 0.0f;                                                             \
        if ((II) >= 0) {                                                        \
            const float zif = (float)(ZI);                                      \
            const float zjf = (float)(ZJ);                                      \
            const float za_i = exp2f_(ae * log2f_(zif));                        \
            const float za_j = exp2f_(ae * log2f_(zjf));                        \
            const float add = 1.0f - (BM);                                      \
            const float dx = (DX) + add, dy = (DY) + add, dz = (DZ) + add;      \
            float d2   = fmaxf(dx * dx + dy * dy + dz * dz, 1e-20f);            \
            float rsq  = rsqf_(d2);                                             \
            float dist = d2 * rsq;                                              \
            float tt = dist * 0.1f;                                             \
            float tc = fminf(fmaxf(tt, 1e-9f), 1.0f - 1e-9f);                   \
            float u  = (1.0f - 2.0f * tc) * rcpf_(tc - tc * tc);                \
            float s  = rcpf_(1.0f + exp2f_(u * LOG2E));                         \
            float sw = (tt >= 1.0f) ? 1.0f : s;                                 \
            float za_sum = za_i + za_j;                                         \
            float arg  = fminf(dist * za_sum * ac_inv, 1e6f);                   \
            float narg = -arg * LOG2E;                                          \
            float phi  = c0 * exp2f_(e0 * narg) + c1 * exp2f_(e1 * narg) +      \
                         c2 * exp2f_(e2 * narg) + c3 * exp2f_(e3 * narg);       \
            phi = fminf(fmaxf(phi, 1e-30f), 1e6f);                              \
            float cp   = fminf(zif * zjf, 1e4f);                                \
            float brep = fminf(0.5f * cp * rsq, 1e6f);                          \
            float r    = brep * phi * fmaxf(sw, 1e-30f);                        \
            r = fminf(fmaxf(r, 0.0f), 1e6f);                                    \
            if (!(r == r)) r = 0.0f;                                            \
            rep = r * (BM);                                                     \
        }                                                                       \
    }

#define DEPOSIT(k, v)                                                           \
    {                                                                           \
        if ((k) >= 0) {                                                         \
            int slot = (k) - kbase;                                             \
            if (slot < CAP) atomicAdd(&s_acc[slot], (v));                       \
            else            atomicAdd(&out_acc[k], (v));                        \
        }                                                                       \
    }

#define MERGE(K, R)                                                             \
    {                                                                           \
        if ((K) == runkey) runsum += (R);                                       \
        else { DEPOSIT(runkey, runsum); runkey = (K); runsum = (R); }           \
    }

    // segmented scan + deposit of a (key,sum) pending pair
#define SCAN_DEPOSIT(PK, PS)                                                    \
    {                                                                           \
        float v = (PS);                                                         \
        int   k = (PK);                                                         \
        _Pragma("unroll")                                                       \
        for (int d = 1; d < 64; d <<= 1) {                                      \
            float nv = __shfl_down(v, d);                                       \
            int   nk = __shfl_down(k, d);                                       \
            if (lane + d < 64 && nk == k) v += nv;                              \
        }                                                                       \
        int pk2 = __shfl_up(k, 1);                                              \
        bool head = (lane == 0) || (pk2 != k);                                  \
        if (head) DEPOSIT(k, v);                                                \
    }

    // ---- prologue: stages 0,1 streams; z for stage 0 (inline)
    G4 s0 = loadG4(idx_i, idx_j, batch_mask, disp, cbeg + tid * PPT,        cend);
    G4 s1 = loadG4(idx_i, idx_j, batch_mask, disp, cbeg + STRD + tid * PPT, cend);
    int czi0 = (int)s_z8[max(s0.ii0, 0)], czj0 = (int)s_z8[s0.jj0];
    int czi1 = (int)s_z8[max(s0.ii1, 0)], czj1 = (int)s_z8[s0.jj1];
    int czi2 = (int)s_z8[max(s0.ii2, 0)], czj2 = (int)s_z8[s0.jj2];
    int czi3 = (int)s_z8[max(s0.ii3, 0)], czj3 = (int)s_z8[s0.jj3];

    int   pkey = -1;
    float psum = 0.0f;

    for (int pb = cbeg; pb < cend; pb += STRD) {
        // A) stream loads for stage t+2 (global, consumed 2 iters later)
        G4 s2 = loadG4(idx_i, idx_j, batch_mask, disp,
                       pb + 2 * STRD + tid * PPT, cend);

        // B) z8 prefetch for stage t+1 (LDS, consumed next iter)
        int nzi0 = (int)s_z8[max(s1.ii0, 0)], nzj0 = (int)s_z8[s1.jj0];
        int nzi1 = (int)s_z8[max(s1.ii1, 0)], nzj1 = (int)s_z8[s1.jj1];
        int nzi2 = (int)s_z8[max(s1.ii2, 0)], nzj2 = (int)s_z8[s1.jj2];
        int nzi3 = (int)s_z8[max(s1.ii3, 0)], nzj3 = (int)s_z8[s1.jj3];

        // C) compute stage t (4 pairs) + local run-merge
        float r0, r1, r2, r3;
        PAIR_REP(s0.ii0, s0.jj0, czi0, czj0, s0.bm0, s0.dx0, s0.dy0, s0.dz0, r0);
        PAIR_REP(s0.ii1, s0.jj1, czi1, czj1, s0.bm1, s0.dx1, s0.dy1, s0.dz1, r1);
        PAIR_REP(s0.ii2, s0.jj2, czi2, czj2, s0.bm2, s0.dx2, s0.dy2, s0.dz2, r2);
        PAIR_REP(s0.ii3, s0.jj3, czi3, czj3, s0.bm3, s0.dx3, s0.dy3, s0.dz3, r3);

        int   runkey = s0.ii0;
        float runsum = r0;
        MERGE(s0.ii1, r1);
        MERGE(s0.ii2, r2);
        MERGE(s0.ii3, r3);

        // D) DEFERRED: scan+deposit of iteration t-1's pending — independent
        //    of C's chain, so the scheduler interleaves them
        SCAN_DEPOSIT(pkey, psum);

        // E) rotate
        s0 = s1; s1 = s2;
        czi0 = nzi0; czj0 = nzj0; czi1 = nzi1; czj1 = nzj1;
        czi2 = nzi2; czj2 = nzj2; czi3 = nzi3; czj3 = nzj3;
        pkey = runkey; psum = runsum;
    }

    // epilogue: flush the last pending
    SCAN_DEPOSIT(pkey, psum);

#undef PAIR_REP
#undef DEPOSIT
#undef MERGE
#undef SCAN_DEPOSIT

    // ---- flush LDS slots to global
    __syncthreads();
    for (int s = tid; s < CAP; s += BLK) {
        float v = s_acc[s];
        int   k = kbase + s;
        if (v != 0.0f && k < nA) atomicAdd(&out_acc[k], v);
    }
}

__global__ void zbl_epilogue(float* __restrict__ out,
                             const float* __restrict__ atom_mask, int n) {
    int i = blockIdx.x * blockDim.x + threadIdx.x;
    if (i >= n) return;
    float v = out[i] * atom_mask[i];
    v = fminf(fmaxf(v, 0.0f), 1e6f);
    if (!(v == v)) v = 0.0f;
    out[i] = v * 0.01f;
}

extern "C" void kernel_launch(void* const* d_in, const int* in_sizes, int n_in,
                              void* d_out, int out_size, void* d_ws, size_t ws_size,
                              hipStream_t stream) {
    const float* an         = (const float*)d_in[0];
    const float* disp       = (const float*)d_in[1];
    const int*   idx_i      = (const int*)d_in[2];
    const int*   idx_j      = (const int*)d_in[3];
    const float* atom_mask  = (const float*)d_in[4];
    const float* batch_mask = (const float*)d_in[5];
    const float* a_coef     = (const float*)d_in[8];
    const float* a_exp      = (const float*)d_in[9];
    const float* phi_c      = (const float*)d_in[10];
    const float* phi_e      = (const float*)d_in[11];

    const int nA = in_sizes[0];
    const int nP = in_sizes[2];
    float* out = (float*)d_out;

    unsigned char* z8 = (unsigned char*)d_ws;

    zbl_k0<<<(nA + 255) / 256, 256, 0, stream>>>(an, z8, out, nA);

    const int nA_pad = (nA + 15) & ~15;
    const size_t smem = (size_t)nA_pad + (size_t)CAP * sizeof(float);
    zbl_pair_kernel<<<NBLK, BLK, smem, stream>>>(
        disp, idx_i, idx_j, batch_mask, z8, a_coef, a_exp, phi_c, phi_e,
        out, nA, nP);

    zbl_epilogue<<<(nA + 255) / 256, 256, 0, stream>>>(out, atom_mask, nA);
}